// Round 8
// baseline (9735.082 us; speedup 1.0000x reference)
//
#include <hip/hip_runtime.h>
#include <stdint.h>

#define B_ 32
#define T_ 256
#define DI_ 512
#define H_ 1024

// R8: EXACT R5 kernel (best measured: pairk 3160us, total 6400us) with ONE
// variable changed: LDS row stride 1032 -> 1036 shorts (518 dwords, 518%32=6,
// 16 MFMA rows hit 16 distinct bank residues; R6 measured conflicts
// 1.32e8 -> 3.98e7). Everything else verbatim R5 for clean bisection.
#define LSTR 1036

using f32x4 = __attribute__((ext_vector_type(4))) float;
using s16x8 = __attribute__((ext_vector_type(8))) short;

__device__ inline unsigned short f2bf(float x) {
    unsigned u = __float_as_uint(x);
    u += 0x7FFFu + ((u >> 16) & 1u);
    return (unsigned short)(u >> 16);
}
__device__ inline float bf2f(unsigned short h) { return __uint_as_float(((unsigned)h) << 16); }
__device__ inline float sigf(float x) { return 1.f / (1.f + __expf(-x)); }
__device__ inline float tanhf_(float x) { return 1.f - 2.f / (__expf(2.f * x) + 1.f); }

__device__ inline unsigned ldA32(const unsigned* p) {
    return __hip_atomic_load(p, __ATOMIC_RELAXED, __HIP_MEMORY_SCOPE_AGENT);
}
__device__ inline void stA32(unsigned* p, unsigned v) {
    __hip_atomic_store(p, v, __ATOMIC_RELAXED, __HIP_MEMORY_SCOPE_AGENT);
}
__device__ inline unsigned long long ldA64(const unsigned long long* p) {
    return __hip_atomic_load(p, __ATOMIC_RELAXED, __HIP_MEMORY_SCOPE_AGENT);
}
__device__ inline void stA64(unsigned long long* p, unsigned long long v) {
    __hip_atomic_store(p, v, __ATOMIC_RELAXED, __HIP_MEMORY_SCOPE_AGENT);
}

// ---------------- conversion kernels ----------------

__global__ void conv_inputs_k(const float* __restrict__ in, unsigned short* __restrict__ out) {
    int idx = blockIdx.x * 256 + threadIdx.x;
    int d = (idx & 127) * 4;
    int row = idx >> 7;
    int t = row >> 5, b = row & 31;
    float4 v = *(const float4*)(in + ((size_t)b * T_ + t) * DI_ + d);
    unsigned long long p = (unsigned long long)f2bf(v.x)
        | ((unsigned long long)f2bf(v.y) << 16)
        | ((unsigned long long)f2bf(v.z) << 32)
        | ((unsigned long long)f2bf(v.w) << 48);
    *(unsigned long long*)(out + (size_t)row * DI_ + d) = p;
}

__global__ void conv_w_k(const float* __restrict__ src, unsigned short* __restrict__ dst,
                         int rowStride, int colOff, int K, int total4) {
    int idx = blockIdx.x * 256 + threadIdx.x;
    if (idx >= total4) return;
    int K4 = K >> 2;
    int r = idx / K4;
    int k = (idx - r * K4) << 2;
    float4 v = *(const float4*)(src + (size_t)r * rowStride + colOff + k);
    unsigned long long p = (unsigned long long)f2bf(v.x)
        | ((unsigned long long)f2bf(v.y) << 16)
        | ((unsigned long long)f2bf(v.z) << 32)
        | ((unsigned long long)f2bf(v.w) << 48);
    *(unsigned long long*)(dst + (size_t)r * K + k) = p;
}

__global__ void bias0_k(const float* __restrict__ a, const float* __restrict__ b, float* __restrict__ o) {
    int i = blockIdx.x * 256 + threadIdx.x;
    if (i < 4 * H_) o[i] = a[i] + b[i];
}

// ---------------- big parallel projection GEMM ----------------
__global__ __launch_bounds__(256) void proj_gemm_k(
    const unsigned short* __restrict__ A, const unsigned short* __restrict__ W,
    const float* __restrict__ bias, unsigned short* __restrict__ out, int K, int N) {
    __shared__ unsigned short Al[128 * 56];
    __shared__ unsigned short Bl[128 * 56];
    const int tid = threadIdx.x;
    const int lane = tid & 63, wave = tid >> 6;
    const int quad = lane >> 4, l16 = lane & 15;
    const int wm = (wave >> 1) * 64, wn = (wave & 1) * 64;
    const int bm = blockIdx.x, bn = blockIdx.y;
    const int srow = tid >> 1, shalf = tid & 1;
    const unsigned short* Ab = A + (size_t)(bm * 128 + srow) * K + shalf * 16;
    const unsigned short* Wb = W + (size_t)(bn * 128 + srow) * K + shalf * 16;

    f32x4 acc[4][4];
#pragma unroll
    for (int i = 0; i < 4; i++)
#pragma unroll
        for (int j = 0; j < 4; j++) acc[i][j] = (f32x4){0.f, 0.f, 0.f, 0.f};

    for (int kb = 0; kb < K; kb += 32) {
        s16x8 a0 = *(const s16x8*)(Ab + kb);
        s16x8 a1 = *(const s16x8*)(Ab + kb + 8);
        s16x8 b0 = *(const s16x8*)(Wb + kb);
        s16x8 b1 = *(const s16x8*)(Wb + kb + 8);
        __syncthreads();
        *(s16x8*)(&Al[srow * 56 + shalf * 16]) = a0;
        *(s16x8*)(&Al[srow * 56 + shalf * 16 + 8]) = a1;
        *(s16x8*)(&Bl[srow * 56 + shalf * 16]) = b0;
        *(s16x8*)(&Bl[srow * 56 + shalf * 16 + 8]) = b1;
        __syncthreads();
        s16x8 af[4], bf[4];
#pragma unroll
        for (int mt = 0; mt < 4; mt++) af[mt] = *(const s16x8*)(&Al[(wm + mt * 16 + l16) * 56 + quad * 8]);
#pragma unroll
        for (int nt = 0; nt < 4; nt++) bf[nt] = *(const s16x8*)(&Bl[(wn + nt * 16 + l16) * 56 + quad * 8]);
#pragma unroll
        for (int mt = 0; mt < 4; mt++)
#pragma unroll
            for (int nt = 0; nt < 4; nt++)
                acc[mt][nt] = __builtin_amdgcn_mfma_f32_16x16x32_bf16(af[mt], bf[nt], acc[mt][nt], 0, 0, 0);
    }
#pragma unroll
    for (int nt = 0; nt < 4; nt++) {
        int col = bn * 128 + wn + nt * 16 + l16;
        float bv = bias[col];
#pragma unroll
        for (int mt = 0; mt < 4; mt++) {
#pragma unroll
            for (int r = 0; r < 4; r++) {
                int rowg = bm * 128 + wm + mt * 16 + quad * 4 + r;
                out[(size_t)rowg * N + col] = f2bf(acc[mt][nt][r] + bv);
            }
        }
    }
}

// ---------------- paired persistent recurrence (layer-wavefront) ----------------
// Structure: EXACT R5 (best measured).  Team A (blockIdx<128) = layer l,
// Team B = layer l+1, 8-slot LLC ring carries {pre,c} blocks A->B with
// 6-step back-pressure.  h exchange: sc1 stores + vmcnt + flag; consumers
// plain-cached loads on fresh-per-t addresses (XCD-L2 dedup).
template <int NGA, bool CAA, bool WRB>
__global__ __launch_bounds__(256, 1) void pairk(
    const float* __restrict__ WsrcA, int wStrideA, int wColOffA,
    const unsigned short* __restrict__ preA, int NA,
    const unsigned short* __restrict__ clowA,
    unsigned short* __restrict__ hbufA,
    const unsigned short* __restrict__ WstreamL,
    const float* __restrict__ biasL,
    unsigned short* __restrict__ ring,
    const float* __restrict__ WsrcB,
    unsigned short* __restrict__ hbufB,
    unsigned short* __restrict__ hrowB,
    unsigned short* __restrict__ cbufB,
    float* __restrict__ outh, float* __restrict__ outc,
    unsigned* __restrict__ flags) {

    __shared__ unsigned short wl[41 * LSTR];              // W_prev rows (+1 zero row)
    __shared__ unsigned short hl[32 * LSTR];              // staged h(t-1)
    __shared__ float gl[32 * 41];                         // own-matvec output
    __shared__ alignas(16) unsigned short gx[1536];       // A: pre(t-1) bf16 | B: staged block
    __shared__ alignas(16) unsigned short csh[2][256];    // A: c history (for emission)
    __shared__ alignas(16) unsigned short hsh[256];
    __shared__ float blds[40];                            // A: bias of layer l+1
    __shared__ unsigned epoch;

    const int tid = threadIdx.x;
    const int lane = tid & 63, wave = tid >> 6;
    const int quad = lane >> 4, l16 = lane & 15;
    const bool isA = (int)blockIdx.x < 128;
    const int wgl = (int)blockIdx.x & 127;
    unsigned* hflag = flags + (isA ? 0 : 128);
    unsigned* preflag = flags + 256;
    unsigned* bflag = flags + 384;
    const int u = tid & 7, b = tid >> 3;
    const int unit = wgl * 8 + u;
    const int mtile = wave & 1, ntile = wave >> 1;

    if (tid == 0) epoch = 0;

    auto stageH = [&](const unsigned short* hb, int tsrc) {
        const int scol = wave * 256 + (lane & 31) * 8;
        const int r0 = lane >> 5;
        const unsigned short* hbase = hb + (size_t)tsrc * (B_ * H_) + scol;
        s16x8 hv[16];
#pragma unroll
        for (int i = 0; i < 16; i++) hv[i] = *(const s16x8*)(hbase + (size_t)(r0 + 2 * i) * H_);
#pragma unroll
        for (int i = 0; i < 16; i++) *(s16x8*)(&hl[(r0 + 2 * i) * LSTR + scol]) = hv[i];
    };

    if (isA) {
        // =================== ROLE A ===================
        constexpr int ROWS = NGA * 8;
        constexpr int NT = (ROWS + 15) / 16;
        for (int i = tid; i < ROWS * 1024; i += 256) {
            int r = i >> 10, k = i & 1023;
            wl[r * LSTR + k] =
                f2bf(WsrcA[(size_t)((r >> 3) * H_ + wgl * 8 + (r & 7)) * wStrideA + wColOffA + k]);
        }
        for (int k = tid; k < LSTR; k += 256) wl[ROWS * LSTR + k] = 0;
        for (int i = tid; i < 40; i += 256) blds[i] = biasL[(i >> 3) * H_ + wgl * 8 + (i & 7)];

        float cst = 0.f;
        unsigned short pg[NGA];
        unsigned short clw = 0;
#pragma unroll
        for (int g = 0; g < NGA; g++) pg[g] = preA[(size_t)b * NA + g * H_ + unit];
        if (CAA) clw = clowA[(size_t)b * H_ + unit];
        __syncthreads();

        auto pollA = [&](unsigned tgt, unsigned btgt, bool useB) {
            if (wave == 0) {
                for (;;) {
                    unsigned f0 = ldA32(hflag + lane);
                    unsigned f1 = ldA32(hflag + 64 + lane);
                    unsigned mn = f0 < f1 ? f0 : f1;
                    bool ok = mn >= tgt;
                    if (useB) ok = ok && (ldA32(bflag + wgl) >= btgt);
                    if (__all((int)ok)) break;
                    __builtin_amdgcn_s_sleep(2);
                }
                __hip_atomic_store(&epoch, tgt, __ATOMIC_RELAXED, __HIP_MEMORY_SCOPE_WORKGROUP);
            } else {
                while (__hip_atomic_load(&epoch, __ATOMIC_RELAXED, __HIP_MEMORY_SCOPE_WORKGROUP) < tgt)
                    __builtin_amdgcn_s_sleep(1);
            }
            asm volatile("" ::: "memory");
        };

        auto jobP = [&](int m, int nt) {
            const unsigned short* ar = &hl[(m * 16 + l16) * LSTR + quad * 8];
            int br = nt * 16 + l16;
            if (br >= ROWS) br = ROWS;
            const unsigned short* wr = &wl[br * LSTR + quad * 8];
            f32x4 a0 = (f32x4){0.f, 0.f, 0.f, 0.f}, a1 = a0, a2 = a0, a3 = a0;
#pragma unroll
            for (int kb = 0; kb < 1024; kb += 128) {
                a0 = __builtin_amdgcn_mfma_f32_16x16x32_bf16(*(const s16x8*)(ar + kb), *(const s16x8*)(wr + kb), a0, 0, 0, 0);
                a1 = __builtin_amdgcn_mfma_f32_16x16x32_bf16(*(const s16x8*)(ar + kb + 32), *(const s16x8*)(wr + kb + 32), a1, 0, 0, 0);
                a2 = __builtin_amdgcn_mfma_f32_16x16x32_bf16(*(const s16x8*)(ar + kb + 64), *(const s16x8*)(wr + kb + 64), a2, 0, 0, 0);
                a3 = __builtin_amdgcn_mfma_f32_16x16x32_bf16(*(const s16x8*)(ar + kb + 96), *(const s16x8*)(wr + kb + 96), a3, 0, 0, 0);
            }
            f32x4 a = (a0 + a1) + (a2 + a3);
            int n = nt * 16 + l16;
            if (n < ROWS) {
#pragma unroll
                for (int r = 0; r < 4; r++) gl[(m * 16 + quad * 4 + r) * 41 + n] = a[r];
            }
        };

        auto jobL = [&](int m, int nt) {  // emission matvec: pre_{l+1} rows
            const unsigned short* ar = &hl[(m * 16 + l16) * LSTR + quad * 8];
            int rr = nt * 16 + l16;
            bool vL = rr < 40;
            int g = vL ? (rr >> 3) : 0;
            const unsigned short* sp = WstreamL + (size_t)(g * H_ + wgl * 8 + (rr & 7)) * H_ + quad * 8;
            const s16x8 z = {0, 0, 0, 0, 0, 0, 0, 0};
            f32x4 a0 = (f32x4){0.f, 0.f, 0.f, 0.f}, a1 = a0, a2 = a0, a3 = a0;
#pragma unroll
            for (int kb = 0; kb < 1024; kb += 128) {
                s16x8 w0 = vL ? *(const s16x8*)(sp + kb) : z;
                s16x8 w1 = vL ? *(const s16x8*)(sp + kb + 32) : z;
                s16x8 w2 = vL ? *(const s16x8*)(sp + kb + 64) : z;
                s16x8 w3 = vL ? *(const s16x8*)(sp + kb + 96) : z;
                a0 = __builtin_amdgcn_mfma_f32_16x16x32_bf16(*(const s16x8*)(ar + kb), w0, a0, 0, 0, 0);
                a1 = __builtin_amdgcn_mfma_f32_16x16x32_bf16(*(const s16x8*)(ar + kb + 32), w1, a1, 0, 0, 0);
                a2 = __builtin_amdgcn_mfma_f32_16x16x32_bf16(*(const s16x8*)(ar + kb + 64), w2, a2, 0, 0, 0);
                a3 = __builtin_amdgcn_mfma_f32_16x16x32_bf16(*(const s16x8*)(ar + kb + 96), w3, a3, 0, 0, 0);
            }
            f32x4 a = (a0 + a1) + (a2 + a3);
            if (vL) {
#pragma unroll
                for (int r = 0; r < 4; r++)
                    gx[(m * 16 + quad * 4 + r) * 40 + rr] = f2bf(a[r] + blds[rr]);
            }
        };

        auto packIssue = [&](int tsrc) {  // wave1: gx(pre(tsrc)) + csh -> ring slot
            unsigned short* base = ring + ((size_t)(tsrc & 7) * 128 + wgl) * 1536;
#pragma unroll
            for (int k = 0; k < 3; k++) {
                int off = (k * 64 + lane) * 8;
                const unsigned long long* src = (off < 1280)
                    ? (const unsigned long long*)&gx[off]
                    : (const unsigned long long*)&csh[tsrc & 1][off - 1280];
                unsigned long long* dst = (unsigned long long*)(base + off);
                stA64(dst, src[0]);
                stA64(dst + 1, src[1]);
            }
        };

        for (int t = 0; t < T_; ++t) {
            if (t > 0) {
                pollA((unsigned)t, (unsigned)(t - 6), t > 6);
                __syncthreads();  // all slack jobL done before hl overwrite
                stageH(hbufA, t - 1);
            }
            __syncthreads();  // hl ready
            if (t > 1 && wave == 1) packIssue(t - 2);
            if (t > 0) {
                jobP(mtile, ntile);
                if (NT == 3 && wave < 2) jobP(wave, 2);
            }
            __syncthreads();  // gl ready (and pack reads done)
            {
                float gate[NGA];
#pragma unroll
                for (int g = 0; g < NGA; g++)
                    gate[g] = bf2f(pg[g]) + ((t > 0) ? gl[b * 41 + g * 8 + u] : 0.f);
                float clv = CAA ? bf2f(clw) : 0.f;
                if (t + 1 < T_) {
#pragma unroll
                    for (int g = 0; g < NGA; g++)
                        pg[g] = preA[(size_t)((t + 1) * B_ + b) * NA + g * H_ + unit];
                    if (CAA) clw = clowA[(size_t)((t + 1) * B_ + b) * H_ + unit];
                }
                float cnew, hval;
                if (CAA) {
                    float iv = sigf(gate[0]);
                    float fp = sigf(gate[1] + 1.f);
                    float fl = sigf(gate[2] + 1.f);
                    float uu = tanhf_(gate[3]);
                    float ov = sigf(gate[4]);
                    cnew = cst * fp + clv * fl + uu * iv;
                    hval = ov * tanhf_(cnew);
                } else {
                    float iv = sigf(gate[0]);
                    float fv = sigf(gate[1]);
                    float gv = tanhf_(gate[2]);
                    float ov = sigf(gate[3]);
                    cnew = fv * cst + iv * gv;
                    hval = ov * tanhf_(cnew);
                }
                cst = cnew;
                csh[t & 1][tid] = f2bf(cnew);
                hsh[tid] = f2bf(hval);
            }
            __syncthreads();  // hsh/csh ready
            if (wave == 3) {
                if (lane < 32) {
                    const unsigned long long* s = (const unsigned long long*)&hsh[lane * 8];
                    unsigned long long* d =
                        (unsigned long long*)(hbufA + ((size_t)t * B_ + lane) * H_ + wgl * 8);
                    stA64(d, s[0]);
                    stA64(d + 1, s[1]);
                }
                asm volatile("s_waitcnt vmcnt(0)" ::: "memory");
                if (lane == 0) stA32(hflag + wgl, (unsigned)(t + 1));
            }
            if (t > 1 && wave == 1) {
                asm volatile("s_waitcnt vmcnt(0)" ::: "memory");
                if (lane == 0) stA32(preflag + wgl, (unsigned)(t - 1));
            }
            // slack: emission matvec pre(t-1) from hl = h(t-1)
            if (t > 0) {
                jobL(mtile, ntile);
                if (wave < 2) jobL(wave, 2);
            }
        }
        // epilogue: publish pre(254) (in gx) then compute+publish pre(255)
        pollA(256u, 250u, true);
        __syncthreads();
        stageH(hbufA, T_ - 1);
        __syncthreads();
        if (wave == 1) packIssue(T_ - 2);
        __syncthreads();  // pack reads of gx done before overwrite
        jobL(mtile, ntile);
        if (wave < 2) jobL(wave, 2);
        __syncthreads();  // gx = pre(255) ready
        if (wave == 1) {
            packIssue(T_ - 1);
            asm volatile("s_waitcnt vmcnt(0)" ::: "memory");
            if (lane == 0) stA32(preflag + wgl, 256u);
        }
    } else {
        // =================== ROLE B ===================
        constexpr int ROWS = 40;
        for (int i = tid; i < ROWS * 1024; i += 256) {
            int r = i >> 10, k = i & 1023;
            wl[r * LSTR + k] =
                f2bf(WsrcB[(size_t)((r >> 3) * H_ + wgl * 8 + (r & 7)) * 2048 + 1024 + k]);
        }
        for (int k = tid; k < LSTR; k += 256) wl[ROWS * LSTR + k] = 0;
        float cst = 0.f;
        __syncthreads();

        auto jobP = [&](int m, int nt) {
            const unsigned short* ar = &hl[(m * 16 + l16) * LSTR + quad * 8];
            int br = nt * 16 + l16;
            if (br >= ROWS) br = ROWS;
            const unsigned short* wr = &wl[br * LSTR + quad * 8];
            f32x4 a0 = (f32x4){0.f, 0.f, 0.f, 0.f}, a1 = a0, a2 = a0, a3 = a0;
#pragma unroll
            for (int kb = 0; kb < 1024; kb += 128) {
                a0 = __builtin_amdgcn_mfma_f32_16x16x32_bf16(*(const s16x8*)(ar + kb), *(const s16x8*)(wr + kb), a0, 0, 0, 0);
                a1 = __builtin_amdgcn_mfma_f32_16x16x32_bf16(*(const s16x8*)(ar + kb + 32), *(const s16x8*)(wr + kb + 32), a1, 0, 0, 0);
                a2 = __builtin_amdgcn_mfma_f32_16x16x32_bf16(*(const s16x8*)(ar + kb + 64), *(const s16x8*)(wr + kb + 64), a2, 0, 0, 0);
                a3 = __builtin_amdgcn_mfma_f32_16x16x32_bf16(*(const s16x8*)(ar + kb + 96), *(const s16x8*)(wr + kb + 96), a3, 0, 0, 0);
            }
            f32x4 a = (a0 + a1) + (a2 + a3);
            int n = nt * 16 + l16;
            if (n < ROWS) {
#pragma unroll
                for (int r = 0; r < 4; r++) gl[(m * 16 + quad * 4 + r) * 41 + n] = a[r];
            }
        };

        for (int t = 0; t < T_; ++t) {
            if (wave == 0) {
                for (;;) {
                    bool ok = ldA32(preflag + wgl) >= (unsigned)(t + 1);
                    if (t > 0) {
                        unsigned f0 = ldA32(hflag + lane);
                        unsigned f1 = ldA32(hflag + 64 + lane);
                        unsigned mn = f0 < f1 ? f0 : f1;
                        ok = ok && (mn >= (unsigned)t);
                    }
                    if (__all((int)ok)) break;
                    __builtin_amdgcn_s_sleep(2);
                }
                __hip_atomic_store(&epoch, (unsigned)(t + 1), __ATOMIC_RELAXED, __HIP_MEMORY_SCOPE_WORKGROUP);
            } else {
                while (__hip_atomic_load(&epoch, __ATOMIC_RELAXED, __HIP_MEMORY_SCOPE_WORKGROUP) < (unsigned)(t + 1))
                    __builtin_amdgcn_s_sleep(1);
            }
            asm volatile("" ::: "memory");
            if (t > 0) stageH(hbufB, t - 1);
            if (wave == 0) {
                // consume block (sc1: ring slots are reused)
                const unsigned short* base = ring + ((size_t)(t & 7) * 128 + wgl) * 1536;
#pragma unroll
                for (int k = 0; k < 3; k++) {
                    int off = (k * 64 + lane) * 8;
                    const unsigned long long* sp = (const unsigned long long*)(base + off);
                    unsigned long long v0 = ldA64(sp);
                    unsigned long long v1 = ldA64(sp + 1);
                    *(unsigned long long*)(&gx[off]) = v0;
                    *(unsigned long long*)(&gx[off + 4]) = v1;
                }
                asm volatile("s_waitcnt vmcnt(0)" ::: "memory");
                if (lane == 0) stA32(bflag + wgl, (unsigned)(t + 1));
            }
            __syncthreads();  // hl + gx ready
            if (t > 0) {
                jobP(mtile, ntile);
                if (wave < 2) jobP(wave, 2);
            }
            __syncthreads();  // gl ready
            {
                float gate[5];
#pragma unroll
                for (int g = 0; g < 5; g++)
                    gate[g] = bf2f(gx[b * 40 + g * 8 + u]) + ((t > 0) ? gl[b * 41 + g * 8 + u] : 0.f);
                float clv = bf2f(gx[1280 + b * 8 + u]);
                float iv = sigf(gate[0]);
                float fp = sigf(gate[1] + 1.f);
                float fl = sigf(gate[2] + 1.f);
                float uu = tanhf_(gate[3]);
                float ov = sigf(gate[4]);
                float cnew = cst * fp + clv * fl + uu * iv;
                float hval = ov * tanhf_(cnew);
                cst = cnew;
                hsh[tid] = f2bf(hval);
                if (WRB) {
                    outh[((size_t)b * T_ + t) * H_ + unit] = hval;
                    outc[((size_t)b * T_ + t) * H_ + unit] = cnew;
                } else {
                    cbufB[((size_t)t * B_ + b) * H_ + unit] = f2bf(cnew);
                }
            }
            __syncthreads();  // hsh ready
            if (!WRB && tid < 32)
                *(s16x8*)(hrowB + ((size_t)t * B_ + tid) * H_ + wgl * 8) = *(const s16x8*)&hsh[tid * 8];
            if (wave == 3) {
                if (lane < 32) {
                    const unsigned long long* s = (const unsigned long long*)&hsh[lane * 8];
                    unsigned long long* d =
                        (unsigned long long*)(hbufB + ((size_t)t * B_ + lane) * H_ + wgl * 8);
                    stA64(d, s[0]);
                    stA64(d + 1, s[1]);
                }
                asm volatile("s_waitcnt vmcnt(0)" ::: "memory");
                if (lane == 0) stA32(hflag + wgl, (unsigned)(t + 1));
            }
        }
    }
}

// ---------------- launcher ----------------

extern "C" void kernel_launch(void* const* d_in, const int* in_sizes, int n_in,
                              void* d_out, int out_size, void* d_ws, size_t ws_size,
                              hipStream_t stream) {
    const float* inputs = (const float*)d_in[0];
    const float* W_ih0 = (const float*)d_in[1];
    const float* W_hh0 = (const float*)d_in[2];
    const float* b_ih0 = (const float*)d_in[3];
    const float* b_hh0 = (const float*)d_in[4];
    const float* W_ca = (const float*)d_in[5];
    const float* b_ca = (const float*)d_in[6];
    float* out = (float*)d_out;

    char* ws = (char*)d_ws;
    unsigned* flags = (unsigned*)ws;                                   // 4 KB (2 pair zones)
    unsigned short* A0 = (unsigned short*)(ws + 4096);                 // 8 MB
    unsigned short* R1 = A0 + (size_t)8192 * 512;                      // 10.5 MB bf16 weight staging
    float* bc0 = (float*)((char*)R1 + 10485760);                       // 16 KB
    unsigned short* pre = (unsigned short*)((char*)bc0 + 16384);       // 84 MB
    unsigned short* hA = pre + (size_t)8192 * 5120;                    // 16 MB
    unsigned short* hB = hA + (size_t)8192 * 1024;                     // 16 MB
    unsigned short* hrow1 = hB + (size_t)8192 * 1024;                  // 16 MB
    unsigned short* c1 = hrow1 + (size_t)8192 * 1024;                  // 16 MB
    unsigned short* ring = c1 + (size_t)8192 * 1024;                   // 3 MB

    hipMemsetAsync(flags, 0, 4096, stream);

    // layer-0 input projection
    conv_inputs_k<<<4096, 256, 0, stream>>>(inputs, A0);
    conv_w_k<<<2048, 256, 0, stream>>>(W_ih0, R1, 512, 0, 512, 4096 * 128);
    bias0_k<<<16, 256, 0, stream>>>(b_ih0, b_hh0, bc0);
    proj_gemm_k<<<dim3(64, 32), 256, 0, stream>>>(A0, R1, bc0, pre, 512, 4096);

    // pair 1: A = layer0 (emits pre_1,c_0), B = layer1 (writes hrow1, c1)
    conv_w_k<<<5120, 256, 0, stream>>>(W_ca + (size_t)0 * 5120 * 2048, R1, 2048, 0, 1024, 5120 * 256);
    pairk<4, false, false><<<256, 256, 0, stream>>>(
        W_hh0, 1024, 0, pre, 4096, nullptr, hA,
        R1, b_ca + 0 * 5120, ring,
        W_ca + (size_t)0 * 5120 * 2048, hB, hrow1, c1, nullptr, nullptr, flags);

    // layer-2 input projection over full h_1
    conv_w_k<<<5120, 256, 0, stream>>>(W_ca + (size_t)1 * 5120 * 2048, R1, 2048, 0, 1024, 5120 * 256);
    proj_gemm_k<<<dim3(64, 40), 256, 0, stream>>>(hrow1, R1, b_ca + 1 * 5120, pre, 1024, 5120);

    // pair 2: A = layer2 (consumes pre_2 + c1, emits pre_3,c_2), B = layer3 (writes out)
    conv_w_k<<<5120, 256, 0, stream>>>(W_ca + (size_t)2 * 5120 * 2048, R1, 2048, 0, 1024, 5120 * 256);
    pairk<5, true, true><<<256, 256, 0, stream>>>(
        W_ca + (size_t)1 * 5120 * 2048, 2048, 1024, pre, 5120, c1, hA,
        R1, b_ca + 2 * 5120, ring,
        W_ca + (size_t)2 * 5120 * 2048, hB, nullptr, nullptr,
        out, out + (size_t)8192 * 1024, flags + 512);
}

// Round 9
// 5285.265 us; speedup vs baseline: 1.8419x; 1.8419x over previous
//
#include <hip/hip_runtime.h>
#include <stdint.h>

#define B_ 32
#define T_ 256
#define DI_ 512
#define H_ 1024

// LDS row stride: MUST be a multiple of 8 shorts (16B) -- R8 bisection proved
// stride 1036 (8B-aligned odd rows) splits every ds_*_b128 into 2 ops: +57%.
// 1032 keeps 16B alignment; its bank pattern already meets the 8-cycle
// structural minimum for wave64 b128 (1KB / 128B-per-clock).
#define LSTR 1032

using f32x4 = __attribute__((ext_vector_type(4))) float;
using s16x8 = __attribute__((ext_vector_type(8))) short;

__device__ inline unsigned short f2bf(float x) {
    unsigned u = __float_as_uint(x);
    u += 0x7FFFu + ((u >> 16) & 1u);
    return (unsigned short)(u >> 16);
}
__device__ inline float bf2f(unsigned short h) { return __uint_as_float(((unsigned)h) << 16); }
__device__ inline float sigf(float x) { return 1.f / (1.f + __expf(-x)); }
__device__ inline float tanhf_(float x) { return 1.f - 2.f / (__expf(2.f * x) + 1.f); }

__device__ inline unsigned ldA32(const unsigned* p) {
    return __hip_atomic_load(p, __ATOMIC_RELAXED, __HIP_MEMORY_SCOPE_AGENT);
}
__device__ inline void stA32(unsigned* p, unsigned v) {
    __hip_atomic_store(p, v, __ATOMIC_RELAXED, __HIP_MEMORY_SCOPE_AGENT);
}
__device__ inline unsigned long long ldA64(const unsigned long long* p) {
    return __hip_atomic_load(p, __ATOMIC_RELAXED, __HIP_MEMORY_SCOPE_AGENT);
}
__device__ inline void stA64(unsigned long long* p, unsigned long long v) {
    __hip_atomic_store(p, v, __ATOMIC_RELAXED, __HIP_MEMORY_SCOPE_AGENT);
}

// ---------------- conversion kernels ----------------

__global__ void conv_inputs_k(const float* __restrict__ in, unsigned short* __restrict__ out) {
    int idx = blockIdx.x * 256 + threadIdx.x;
    int d = (idx & 127) * 4;
    int row = idx >> 7;
    int t = row >> 5, b = row & 31;
    float4 v = *(const float4*)(in + ((size_t)b * T_ + t) * DI_ + d);
    unsigned long long p = (unsigned long long)f2bf(v.x)
        | ((unsigned long long)f2bf(v.y) << 16)
        | ((unsigned long long)f2bf(v.z) << 32)
        | ((unsigned long long)f2bf(v.w) << 48);
    *(unsigned long long*)(out + (size_t)row * DI_ + d) = p;
}

__global__ void conv_w_k(const float* __restrict__ src, unsigned short* __restrict__ dst,
                         int rowStride, int colOff, int K, int total4) {
    int idx = blockIdx.x * 256 + threadIdx.x;
    if (idx >= total4) return;
    int K4 = K >> 2;
    int r = idx / K4;
    int k = (idx - r * K4) << 2;
    float4 v = *(const float4*)(src + (size_t)r * rowStride + colOff + k);
    unsigned long long p = (unsigned long long)f2bf(v.x)
        | ((unsigned long long)f2bf(v.y) << 16)
        | ((unsigned long long)f2bf(v.z) << 32)
        | ((unsigned long long)f2bf(v.w) << 48);
    *(unsigned long long*)(dst + (size_t)r * K + k) = p;
}

__global__ void bias0_k(const float* __restrict__ a, const float* __restrict__ b, float* __restrict__ o) {
    int i = blockIdx.x * 256 + threadIdx.x;
    if (i < 4 * H_) o[i] = a[i] + b[i];
}

// ---------------- big parallel projection GEMM ----------------
__global__ __launch_bounds__(256) void proj_gemm_k(
    const unsigned short* __restrict__ A, const unsigned short* __restrict__ W,
    const float* __restrict__ bias, unsigned short* __restrict__ out, int K, int N) {
    __shared__ unsigned short Al[128 * 56];
    __shared__ unsigned short Bl[128 * 56];
    const int tid = threadIdx.x;
    const int lane = tid & 63, wave = tid >> 6;
    const int quad = lane >> 4, l16 = lane & 15;
    const int wm = (wave >> 1) * 64, wn = (wave & 1) * 64;
    const int bm = blockIdx.x, bn = blockIdx.y;
    const int srow = tid >> 1, shalf = tid & 1;
    const unsigned short* Ab = A + (size_t)(bm * 128 + srow) * K + shalf * 16;
    const unsigned short* Wb = W + (size_t)(bn * 128 + srow) * K + shalf * 16;

    f32x4 acc[4][4];
#pragma unroll
    for (int i = 0; i < 4; i++)
#pragma unroll
        for (int j = 0; j < 4; j++) acc[i][j] = (f32x4){0.f, 0.f, 0.f, 0.f};

    for (int kb = 0; kb < K; kb += 32) {
        s16x8 a0 = *(const s16x8*)(Ab + kb);
        s16x8 a1 = *(const s16x8*)(Ab + kb + 8);
        s16x8 b0 = *(const s16x8*)(Wb + kb);
        s16x8 b1 = *(const s16x8*)(Wb + kb + 8);
        __syncthreads();
        *(s16x8*)(&Al[srow * 56 + shalf * 16]) = a0;
        *(s16x8*)(&Al[srow * 56 + shalf * 16 + 8]) = a1;
        *(s16x8*)(&Bl[srow * 56 + shalf * 16]) = b0;
        *(s16x8*)(&Bl[srow * 56 + shalf * 16 + 8]) = b1;
        __syncthreads();
        s16x8 af[4], bf[4];
#pragma unroll
        for (int mt = 0; mt < 4; mt++) af[mt] = *(const s16x8*)(&Al[(wm + mt * 16 + l16) * 56 + quad * 8]);
#pragma unroll
        for (int nt = 0; nt < 4; nt++) bf[nt] = *(const s16x8*)(&Bl[(wn + nt * 16 + l16) * 56 + quad * 8]);
#pragma unroll
        for (int mt = 0; mt < 4; mt++)
#pragma unroll
            for (int nt = 0; nt < 4; nt++)
                acc[mt][nt] = __builtin_amdgcn_mfma_f32_16x16x32_bf16(af[mt], bf[nt], acc[mt][nt], 0, 0, 0);
    }
#pragma unroll
    for (int nt = 0; nt < 4; nt++) {
        int col = bn * 128 + wn + nt * 16 + l16;
        float bv = bias[col];
#pragma unroll
        for (int mt = 0; mt < 4; mt++) {
#pragma unroll
            for (int r = 0; r < 4; r++) {
                int rowg = bm * 128 + wm + mt * 16 + quad * 4 + r;
                out[(size_t)rowg * N + col] = f2bf(acc[mt][nt][r] + bv);
            }
        }
    }
}

// ---------------- paired persistent recurrence (layer-wavefront) ----------------
// R9 = EXACT R5 structure (best measured: pairk 3160us) + register-resident
// primary W fragments.  At 1 WG/CU x 4 waves = 1 wave/SIMD, VGPR budget is
// 512/wave (we used 132).  Each wave's PRIMARY jobP/jobL weight rows are
// time-invariant -> hoist 32x s16x8 (=128 VGPR) each into registers once,
// eliminating per-beat 32 ds_read_b128 (jobP) + 32 L2 global loads (jobL,
// fully latency-exposed at 1 wave/SIMD).  Secondary jobs keep streaming.
template <int NGA, bool CAA, bool WRB>
__global__ __launch_bounds__(256, 1) void pairk(
    const float* __restrict__ WsrcA, int wStrideA, int wColOffA,
    const unsigned short* __restrict__ preA, int NA,
    const unsigned short* __restrict__ clowA,
    unsigned short* __restrict__ hbufA,
    const unsigned short* __restrict__ WstreamL,
    const float* __restrict__ biasL,
    unsigned short* __restrict__ ring,
    const float* __restrict__ WsrcB,
    unsigned short* __restrict__ hbufB,
    unsigned short* __restrict__ hrowB,
    unsigned short* __restrict__ cbufB,
    float* __restrict__ outh, float* __restrict__ outc,
    unsigned* __restrict__ flags) {

    __shared__ unsigned short wl[41 * LSTR];              // W_prev rows (+1 zero row)
    __shared__ unsigned short hl[32 * LSTR];              // staged h(t-1)
    __shared__ float gl[32 * 41];                         // own-matvec output
    __shared__ alignas(16) unsigned short gx[1536];       // A: pre(t-1) bf16 | B: staged block
    __shared__ alignas(16) unsigned short csh[2][256];    // A: c history (for emission)
    __shared__ alignas(16) unsigned short hsh[256];
    __shared__ float blds[40];                            // A: bias of layer l+1
    __shared__ unsigned epoch;

    const int tid = threadIdx.x;
    const int lane = tid & 63, wave = tid >> 6;
    const int quad = lane >> 4, l16 = lane & 15;
    const bool isA = (int)blockIdx.x < 128;
    const int wgl = (int)blockIdx.x & 127;
    unsigned* hflag = flags + (isA ? 0 : 128);
    unsigned* preflag = flags + 256;
    unsigned* bflag = flags + 384;
    const int u = tid & 7, b = tid >> 3;
    const int unit = wgl * 8 + u;
    const int mtile = wave & 1, ntile = wave >> 1;
    const s16x8 zv = {0, 0, 0, 0, 0, 0, 0, 0};

    if (tid == 0) epoch = 0;

    auto stageH = [&](const unsigned short* hb, int tsrc) {
        const int scol = wave * 256 + (lane & 31) * 8;
        const int r0 = lane >> 5;
        const unsigned short* hbase = hb + (size_t)tsrc * (B_ * H_) + scol;
        s16x8 hv[16];
#pragma unroll
        for (int i = 0; i < 16; i++) hv[i] = *(const s16x8*)(hbase + (size_t)(r0 + 2 * i) * H_);
#pragma unroll
        for (int i = 0; i < 16; i++) *(s16x8*)(&hl[(r0 + 2 * i) * LSTR + scol]) = hv[i];
    };

    if (isA) {
        // =================== ROLE A ===================
        constexpr int ROWS = NGA * 8;
        constexpr int NT = (ROWS + 15) / 16;
        for (int i = tid; i < ROWS * 1024; i += 256) {
            int r = i >> 10, k = i & 1023;
            wl[r * LSTR + k] =
                f2bf(WsrcA[(size_t)((r >> 3) * H_ + wgl * 8 + (r & 7)) * wStrideA + wColOffA + k]);
        }
        for (int k = tid; k < LSTR; k += 256) wl[ROWS * LSTR + k] = 0;
        for (int i = tid; i < 40; i += 256) blds[i] = biasL[(i >> 3) * H_ + wgl * 8 + (i & 7)];

        float cst = 0.f;
        unsigned short pg[NGA];
        unsigned short clw = 0;
#pragma unroll
        for (int g = 0; g < NGA; g++) pg[g] = preA[(size_t)b * NA + g * H_ + unit];
        if (CAA) clw = clowA[(size_t)b * H_ + unit];
        __syncthreads();  // wl ready

        // ---- hoist primary W fragments into registers (time-invariant) ----
        s16x8 wP[32], wL[32];
        {
            int br = ntile * 16 + l16;
            if (br >= ROWS) br = ROWS;
            const unsigned short* wr = &wl[br * LSTR + quad * 8];
#pragma unroll
            for (int c = 0; c < 8; c++)
#pragma unroll
                for (int j = 0; j < 4; j++)
                    wP[c * 4 + j] = *(const s16x8*)(wr + c * 128 + j * 32);
        }
        {
            int rr = ntile * 16 + l16;
            bool vL = rr < 40;
            int g = vL ? (rr >> 3) : 0;
            const unsigned short* sp =
                WstreamL + (size_t)(g * H_ + wgl * 8 + (rr & 7)) * H_ + quad * 8;
#pragma unroll
            for (int c = 0; c < 8; c++)
#pragma unroll
                for (int j = 0; j < 4; j++)
                    wL[c * 4 + j] = vL ? *(const s16x8*)(sp + c * 128 + j * 32) : zv;
        }

        auto pollA = [&](unsigned tgt, unsigned btgt, bool useB) {
            if (wave == 0) {
                for (;;) {
                    unsigned f0 = ldA32(hflag + lane);
                    unsigned f1 = ldA32(hflag + 64 + lane);
                    unsigned mn = f0 < f1 ? f0 : f1;
                    bool ok = mn >= tgt;
                    if (useB) ok = ok && (ldA32(bflag + wgl) >= btgt);
                    if (__all((int)ok)) break;
                    __builtin_amdgcn_s_sleep(2);
                }
                __hip_atomic_store(&epoch, tgt, __ATOMIC_RELAXED, __HIP_MEMORY_SCOPE_WORKGROUP);
            } else {
                while (__hip_atomic_load(&epoch, __ATOMIC_RELAXED, __HIP_MEMORY_SCOPE_WORKGROUP) < tgt)
                    __builtin_amdgcn_s_sleep(1);
            }
            asm volatile("" ::: "memory");
        };

        // primary jobP: register W
        auto jobPreg = [&]() {
            const unsigned short* ar = &hl[(mtile * 16 + l16) * LSTR + quad * 8];
            f32x4 a0 = (f32x4){0.f, 0.f, 0.f, 0.f}, a1 = a0, a2 = a0, a3 = a0;
#pragma unroll
            for (int c = 0; c < 8; c++) {
                a0 = __builtin_amdgcn_mfma_f32_16x16x32_bf16(*(const s16x8*)(ar + c * 128), wP[c * 4 + 0], a0, 0, 0, 0);
                a1 = __builtin_amdgcn_mfma_f32_16x16x32_bf16(*(const s16x8*)(ar + c * 128 + 32), wP[c * 4 + 1], a1, 0, 0, 0);
                a2 = __builtin_amdgcn_mfma_f32_16x16x32_bf16(*(const s16x8*)(ar + c * 128 + 64), wP[c * 4 + 2], a2, 0, 0, 0);
                a3 = __builtin_amdgcn_mfma_f32_16x16x32_bf16(*(const s16x8*)(ar + c * 128 + 96), wP[c * 4 + 3], a3, 0, 0, 0);
            }
            f32x4 a = (a0 + a1) + (a2 + a3);
            int n = ntile * 16 + l16;
            if (n < ROWS) {
#pragma unroll
                for (int r = 0; r < 4; r++) gl[(mtile * 16 + quad * 4 + r) * 41 + n] = a[r];
            }
        };

        auto jobP = [&](int m, int nt) {  // secondary: streams wl from LDS
            const unsigned short* ar = &hl[(m * 16 + l16) * LSTR + quad * 8];
            int br = nt * 16 + l16;
            if (br >= ROWS) br = ROWS;
            const unsigned short* wr = &wl[br * LSTR + quad * 8];
            f32x4 a0 = (f32x4){0.f, 0.f, 0.f, 0.f}, a1 = a0, a2 = a0, a3 = a0;
#pragma unroll
            for (int kb = 0; kb < 1024; kb += 128) {
                a0 = __builtin_amdgcn_mfma_f32_16x16x32_bf16(*(const s16x8*)(ar + kb), *(const s16x8*)(wr + kb), a0, 0, 0, 0);
                a1 = __builtin_amdgcn_mfma_f32_16x16x32_bf16(*(const s16x8*)(ar + kb + 32), *(const s16x8*)(wr + kb + 32), a1, 0, 0, 0);
                a2 = __builtin_amdgcn_mfma_f32_16x16x32_bf16(*(const s16x8*)(ar + kb + 64), *(const s16x8*)(wr + kb + 64), a2, 0, 0, 0);
                a3 = __builtin_amdgcn_mfma_f32_16x16x32_bf16(*(const s16x8*)(ar + kb + 96), *(const s16x8*)(wr + kb + 96), a3, 0, 0, 0);
            }
            f32x4 a = (a0 + a1) + (a2 + a3);
            int n = nt * 16 + l16;
            if (n < ROWS) {
#pragma unroll
                for (int r = 0; r < 4; r++) gl[(m * 16 + quad * 4 + r) * 41 + n] = a[r];
            }
        };

        // primary jobL: register W
        auto jobLreg = [&]() {
            const unsigned short* ar = &hl[(mtile * 16 + l16) * LSTR + quad * 8];
            int rr = ntile * 16 + l16;
            f32x4 a0 = (f32x4){0.f, 0.f, 0.f, 0.f}, a1 = a0, a2 = a0, a3 = a0;
#pragma unroll
            for (int c = 0; c < 8; c++) {
                a0 = __builtin_amdgcn_mfma_f32_16x16x32_bf16(*(const s16x8*)(ar + c * 128), wL[c * 4 + 0], a0, 0, 0, 0);
                a1 = __builtin_amdgcn_mfma_f32_16x16x32_bf16(*(const s16x8*)(ar + c * 128 + 32), wL[c * 4 + 1], a1, 0, 0, 0);
                a2 = __builtin_amdgcn_mfma_f32_16x16x32_bf16(*(const s16x8*)(ar + c * 128 + 64), wL[c * 4 + 2], a2, 0, 0, 0);
                a3 = __builtin_amdgcn_mfma_f32_16x16x32_bf16(*(const s16x8*)(ar + c * 128 + 96), wL[c * 4 + 3], a3, 0, 0, 0);
            }
            f32x4 a = (a0 + a1) + (a2 + a3);
            if (rr < 40) {
#pragma unroll
                for (int r = 0; r < 4; r++)
                    gx[(mtile * 16 + quad * 4 + r) * 40 + rr] = f2bf(a[r] + blds[rr]);
            }
        };

        auto jobL = [&](int m, int nt) {  // secondary: streams W from global (L2)
            const unsigned short* ar = &hl[(m * 16 + l16) * LSTR + quad * 8];
            int rr = nt * 16 + l16;
            bool vL = rr < 40;
            int g = vL ? (rr >> 3) : 0;
            const unsigned short* sp = WstreamL + (size_t)(g * H_ + wgl * 8 + (rr & 7)) * H_ + quad * 8;
            f32x4 a0 = (f32x4){0.f, 0.f, 0.f, 0.f}, a1 = a0, a2 = a0, a3 = a0;
#pragma unroll
            for (int kb = 0; kb < 1024; kb += 128) {
                s16x8 w0 = vL ? *(const s16x8*)(sp + kb) : zv;
                s16x8 w1 = vL ? *(const s16x8*)(sp + kb + 32) : zv;
                s16x8 w2 = vL ? *(const s16x8*)(sp + kb + 64) : zv;
                s16x8 w3 = vL ? *(const s16x8*)(sp + kb + 96) : zv;
                a0 = __builtin_amdgcn_mfma_f32_16x16x32_bf16(*(const s16x8*)(ar + kb), w0, a0, 0, 0, 0);
                a1 = __builtin_amdgcn_mfma_f32_16x16x32_bf16(*(const s16x8*)(ar + kb + 32), w1, a1, 0, 0, 0);
                a2 = __builtin_amdgcn_mfma_f32_16x16x32_bf16(*(const s16x8*)(ar + kb + 64), w2, a2, 0, 0, 0);
                a3 = __builtin_amdgcn_mfma_f32_16x16x32_bf16(*(const s16x8*)(ar + kb + 96), w3, a3, 0, 0, 0);
            }
            f32x4 a = (a0 + a1) + (a2 + a3);
            if (vL) {
#pragma unroll
                for (int r = 0; r < 4; r++)
                    gx[(m * 16 + quad * 4 + r) * 40 + rr] = f2bf(a[r] + blds[rr]);
            }
        };

        auto packIssue = [&](int tsrc) {  // wave1: gx(pre(tsrc)) + csh -> ring slot
            unsigned short* base = ring + ((size_t)(tsrc & 7) * 128 + wgl) * 1536;
#pragma unroll
            for (int k = 0; k < 3; k++) {
                int off = (k * 64 + lane) * 8;
                const unsigned long long* src = (off < 1280)
                    ? (const unsigned long long*)&gx[off]
                    : (const unsigned long long*)&csh[tsrc & 1][off - 1280];
                unsigned long long* dst = (unsigned long long*)(base + off);
                stA64(dst, src[0]);
                stA64(dst + 1, src[1]);
            }
        };

        for (int t = 0; t < T_; ++t) {
            if (t > 0) {
                pollA((unsigned)t, (unsigned)(t - 6), t > 6);
                __syncthreads();  // all slack jobL done before hl overwrite
                stageH(hbufA, t - 1);
            }
            __syncthreads();  // hl ready
            if (t > 1 && wave == 1) packIssue(t - 2);
            if (t > 0) {
                jobPreg();
                if (NT == 3 && wave < 2) jobP(wave, 2);
            }
            __syncthreads();  // gl ready (and pack reads done)
            {
                float gate[NGA];
#pragma unroll
                for (int g = 0; g < NGA; g++)
                    gate[g] = bf2f(pg[g]) + ((t > 0) ? gl[b * 41 + g * 8 + u] : 0.f);
                float clv = CAA ? bf2f(clw) : 0.f;
                if (t + 1 < T_) {
#pragma unroll
                    for (int g = 0; g < NGA; g++)
                        pg[g] = preA[(size_t)((t + 1) * B_ + b) * NA + g * H_ + unit];
                    if (CAA) clw = clowA[(size_t)((t + 1) * B_ + b) * H_ + unit];
                }
                float cnew, hval;
                if (CAA) {
                    float iv = sigf(gate[0]);
                    float fp = sigf(gate[1] + 1.f);
                    float fl = sigf(gate[2] + 1.f);
                    float uu = tanhf_(gate[3]);
                    float ov = sigf(gate[4]);
                    cnew = cst * fp + clv * fl + uu * iv;
                    hval = ov * tanhf_(cnew);
                } else {
                    float iv = sigf(gate[0]);
                    float fv = sigf(gate[1]);
                    float gv = tanhf_(gate[2]);
                    float ov = sigf(gate[3]);
                    cnew = fv * cst + iv * gv;
                    hval = ov * tanhf_(cnew);
                }
                cst = cnew;
                csh[t & 1][tid] = f2bf(cnew);
                hsh[tid] = f2bf(hval);
            }
            __syncthreads();  // hsh/csh ready
            if (wave == 3) {
                if (lane < 32) {
                    const unsigned long long* s = (const unsigned long long*)&hsh[lane * 8];
                    unsigned long long* d =
                        (unsigned long long*)(hbufA + ((size_t)t * B_ + lane) * H_ + wgl * 8);
                    stA64(d, s[0]);
                    stA64(d + 1, s[1]);
                }
                asm volatile("s_waitcnt vmcnt(0)" ::: "memory");
                if (lane == 0) stA32(hflag + wgl, (unsigned)(t + 1));
            }
            if (t > 1 && wave == 1) {
                asm volatile("s_waitcnt vmcnt(0)" ::: "memory");
                if (lane == 0) stA32(preflag + wgl, (unsigned)(t - 1));
            }
            // slack: emission matvec pre(t-1) from hl = h(t-1)
            if (t > 0) {
                jobLreg();
                if (wave < 2) jobL(wave, 2);
            }
        }
        // epilogue: publish pre(254) (in gx) then compute+publish pre(255)
        pollA(256u, 250u, true);
        __syncthreads();
        stageH(hbufA, T_ - 1);
        __syncthreads();
        if (wave == 1) packIssue(T_ - 2);
        __syncthreads();  // pack reads of gx done before overwrite
        jobLreg();
        if (wave < 2) jobL(wave, 2);
        __syncthreads();  // gx = pre(255) ready
        if (wave == 1) {
            packIssue(T_ - 1);
            asm volatile("s_waitcnt vmcnt(0)" ::: "memory");
            if (lane == 0) stA32(preflag + wgl, 256u);
        }
    } else {
        // =================== ROLE B ===================
        constexpr int ROWS = 40;
        for (int i = tid; i < ROWS * 1024; i += 256) {
            int r = i >> 10, k = i & 1023;
            wl[r * LSTR + k] =
                f2bf(WsrcB[(size_t)((r >> 3) * H_ + wgl * 8 + (r & 7)) * 2048 + 1024 + k]);
        }
        for (int k = tid; k < LSTR; k += 256) wl[ROWS * LSTR + k] = 0;
        float cst = 0.f;
        __syncthreads();

        // hoist primary jobP W fragment
        s16x8 wP[32];
        {
            int br = ntile * 16 + l16;
            if (br >= ROWS) br = ROWS;
            const unsigned short* wr = &wl[br * LSTR + quad * 8];
#pragma unroll
            for (int c = 0; c < 8; c++)
#pragma unroll
                for (int j = 0; j < 4; j++)
                    wP[c * 4 + j] = *(const s16x8*)(wr + c * 128 + j * 32);
        }

        auto jobPreg = [&]() {
            const unsigned short* ar = &hl[(mtile * 16 + l16) * LSTR + quad * 8];
            f32x4 a0 = (f32x4){0.f, 0.f, 0.f, 0.f}, a1 = a0, a2 = a0, a3 = a0;
#pragma unroll
            for (int c = 0; c < 8; c++) {
                a0 = __builtin_amdgcn_mfma_f32_16x16x32_bf16(*(const s16x8*)(ar + c * 128), wP[c * 4 + 0], a0, 0, 0, 0);
                a1 = __builtin_amdgcn_mfma_f32_16x16x32_bf16(*(const s16x8*)(ar + c * 128 + 32), wP[c * 4 + 1], a1, 0, 0, 0);
                a2 = __builtin_amdgcn_mfma_f32_16x16x32_bf16(*(const s16x8*)(ar + c * 128 + 64), wP[c * 4 + 2], a2, 0, 0, 0);
                a3 = __builtin_amdgcn_mfma_f32_16x16x32_bf16(*(const s16x8*)(ar + c * 128 + 96), wP[c * 4 + 3], a3, 0, 0, 0);
            }
            f32x4 a = (a0 + a1) + (a2 + a3);
            int n = ntile * 16 + l16;
            if (n < ROWS) {
#pragma unroll
                for (int r = 0; r < 4; r++) gl[(mtile * 16 + quad * 4 + r) * 41 + n] = a[r];
            }
        };

        auto jobP = [&](int m, int nt) {
            const unsigned short* ar = &hl[(m * 16 + l16) * LSTR + quad * 8];
            int br = nt * 16 + l16;
            if (br >= ROWS) br = ROWS;
            const unsigned short* wr = &wl[br * LSTR + quad * 8];
            f32x4 a0 = (f32x4){0.f, 0.f, 0.f, 0.f}, a1 = a0, a2 = a0, a3 = a0;
#pragma unroll
            for (int kb = 0; kb < 1024; kb += 128) {
                a0 = __builtin_amdgcn_mfma_f32_16x16x32_bf16(*(const s16x8*)(ar + kb), *(const s16x8*)(wr + kb), a0, 0, 0, 0);
                a1 = __builtin_amdgcn_mfma_f32_16x16x32_bf16(*(const s16x8*)(ar + kb + 32), *(const s16x8*)(wr + kb + 32), a1, 0, 0, 0);
                a2 = __builtin_amdgcn_mfma_f32_16x16x32_bf16(*(const s16x8*)(ar + kb + 64), *(const s16x8*)(wr + kb + 64), a2, 0, 0, 0);
                a3 = __builtin_amdgcn_mfma_f32_16x16x32_bf16(*(const s16x8*)(ar + kb + 96), *(const s16x8*)(wr + kb + 96), a3, 0, 0, 0);
            }
            f32x4 a = (a0 + a1) + (a2 + a3);
            int n = nt * 16 + l16;
            if (n < ROWS) {
#pragma unroll
                for (int r = 0; r < 4; r++) gl[(m * 16 + quad * 4 + r) * 41 + n] = a[r];
            }
        };

        for (int t = 0; t < T_; ++t) {
            if (wave == 0) {
                for (;;) {
                    bool ok = ldA32(preflag + wgl) >= (unsigned)(t + 1);
                    if (t > 0) {
                        unsigned f0 = ldA32(hflag + lane);
                        unsigned f1 = ldA32(hflag + 64 + lane);
                        unsigned mn = f0 < f1 ? f0 : f1;
                        ok = ok && (mn >= (unsigned)t);
                    }
                    if (__all((int)ok)) break;
                    __builtin_amdgcn_s_sleep(2);
                }
                __hip_atomic_store(&epoch, (unsigned)(t + 1), __ATOMIC_RELAXED, __HIP_MEMORY_SCOPE_WORKGROUP);
            } else {
                while (__hip_atomic_load(&epoch, __ATOMIC_RELAXED, __HIP_MEMORY_SCOPE_WORKGROUP) < (unsigned)(t + 1))
                    __builtin_amdgcn_s_sleep(1);
            }
            asm volatile("" ::: "memory");
            if (t > 0) stageH(hbufB, t - 1);
            if (wave == 0) {
                // consume block (sc1: ring slots are reused)
                const unsigned short* base = ring + ((size_t)(t & 7) * 128 + wgl) * 1536;
#pragma unroll
                for (int k = 0; k < 3; k++) {
                    int off = (k * 64 + lane) * 8;
                    const unsigned long long* sp = (const unsigned long long*)(base + off);
                    unsigned long long v0 = ldA64(sp);
                    unsigned long long v1 = ldA64(sp + 1);
                    *(unsigned long long*)(&gx[off]) = v0;
                    *(unsigned long long*)(&gx[off + 4]) = v1;
                }
                asm volatile("s_waitcnt vmcnt(0)" ::: "memory");
                if (lane == 0) stA32(bflag + wgl, (unsigned)(t + 1));
            }
            __syncthreads();  // hl + gx ready
            if (t > 0) {
                jobPreg();
                if (wave < 2) jobP(wave, 2);
            }
            __syncthreads();  // gl ready
            {
                float gate[5];
#pragma unroll
                for (int g = 0; g < 5; g++)
                    gate[g] = bf2f(gx[b * 40 + g * 8 + u]) + ((t > 0) ? gl[b * 41 + g * 8 + u] : 0.f);
                float clv = bf2f(gx[1280 + b * 8 + u]);
                float iv = sigf(gate[0]);
                float fp = sigf(gate[1] + 1.f);
                float fl = sigf(gate[2] + 1.f);
                float uu = tanhf_(gate[3]);
                float ov = sigf(gate[4]);
                float cnew = cst * fp + clv * fl + uu * iv;
                float hval = ov * tanhf_(cnew);
                cst = cnew;
                hsh[tid] = f2bf(hval);
                if (WRB) {
                    outh[((size_t)b * T_ + t) * H_ + unit] = hval;
                    outc[((size_t)b * T_ + t) * H_ + unit] = cnew;
                } else {
                    cbufB[((size_t)t * B_ + b) * H_ + unit] = f2bf(cnew);
                }
            }
            __syncthreads();  // hsh ready
            if (!WRB && tid < 32)
                *(s16x8*)(hrowB + ((size_t)t * B_ + tid) * H_ + wgl * 8) = *(const s16x8*)&hsh[tid * 8];
            if (wave == 3) {
                if (lane < 32) {
                    const unsigned long long* s = (const unsigned long long*)&hsh[lane * 8];
                    unsigned long long* d =
                        (unsigned long long*)(hbufB + ((size_t)t * B_ + lane) * H_ + wgl * 8);
                    stA64(d, s[0]);
                    stA64(d + 1, s[1]);
                }
                asm volatile("s_waitcnt vmcnt(0)" ::: "memory");
                if (lane == 0) stA32(hflag + wgl, (unsigned)(t + 1));
            }
        }
    }
}

// ---------------- launcher ----------------

extern "C" void kernel_launch(void* const* d_in, const int* in_sizes, int n_in,
                              void* d_out, int out_size, void* d_ws, size_t ws_size,
                              hipStream_t stream) {
    const float* inputs = (const float*)d_in[0];
    const float* W_ih0 = (const float*)d_in[1];
    const float* W_hh0 = (const float*)d_in[2];
    const float* b_ih0 = (const float*)d_in[3];
    const float* b_hh0 = (const float*)d_in[4];
    const float* W_ca = (const float*)d_in[5];
    const float* b_ca = (const float*)d_in[6];
    float* out = (float*)d_out;

    char* ws = (char*)d_ws;
    unsigned* flags = (unsigned*)ws;                                   // 4 KB (2 pair zones)
    unsigned short* A0 = (unsigned short*)(ws + 4096);                 // 8 MB
    unsigned short* R1 = A0 + (size_t)8192 * 512;                      // 10.5 MB bf16 weight staging
    float* bc0 = (float*)((char*)R1 + 10485760);                       // 16 KB
    unsigned short* pre = (unsigned short*)((char*)bc0 + 16384);       // 84 MB
    unsigned short* hA = pre + (size_t)8192 * 5120;                    // 16 MB
    unsigned short* hB = hA + (size_t)8192 * 1024;                     // 16 MB
    unsigned short* hrow1 = hB + (size_t)8192 * 1024;                  // 16 MB
    unsigned short* c1 = hrow1 + (size_t)8192 * 1024;                  // 16 MB
    unsigned short* ring = c1 + (size_t)8192 * 1024;                   // 3 MB

    hipMemsetAsync(flags, 0, 4096, stream);

    // layer-0 input projection
    conv_inputs_k<<<4096, 256, 0, stream>>>(inputs, A0);
    conv_w_k<<<2048, 256, 0, stream>>>(W_ih0, R1, 512, 0, 512, 4096 * 128);
    bias0_k<<<16, 256, 0, stream>>>(b_ih0, b_hh0, bc0);
    proj_gemm_k<<<dim3(64, 32), 256, 0, stream>>>(A0, R1, bc0, pre, 512, 4096);

    // pair 1: A = layer0 (emits pre_1,c_0), B = layer1 (writes hrow1, c1)
    conv_w_k<<<5120, 256, 0, stream>>>(W_ca + (size_t)0 * 5120 * 2048, R1, 2048, 0, 1024, 5120 * 256);
    pairk<4, false, false><<<256, 256, 0, stream>>>(
        W_hh0, 1024, 0, pre, 4096, nullptr, hA,
        R1, b_ca + 0 * 5120, ring,
        W_ca + (size_t)0 * 5120 * 2048, hB, hrow1, c1, nullptr, nullptr, flags);

    // layer-2 input projection over full h_1
    conv_w_k<<<5120, 256, 0, stream>>>(W_ca + (size_t)1 * 5120 * 2048, R1, 2048, 0, 1024, 5120 * 256);
    proj_gemm_k<<<dim3(64, 40), 256, 0, stream>>>(hrow1, R1, b_ca + 1 * 5120, pre, 1024, 5120);

    // pair 2: A = layer2 (consumes pre_2 + c1, emits pre_3,c_2), B = layer3 (writes out)
    conv_w_k<<<5120, 256, 0, stream>>>(W_ca + (size_t)2 * 5120 * 2048, R1, 2048, 0, 1024, 5120 * 256);
    pairk<5, true, true><<<256, 256, 0, stream>>>(
        W_ca + (size_t)1 * 5120 * 2048, 2048, 1024, pre, 5120, c1, hA,
        R1, b_ca + 2 * 5120, ring,
        W_ca + (size_t)2 * 5120 * 2048, hB, nullptr, nullptr,
        out, out + (size_t)8192 * 1024, flags + 512);
}

// Round 10
// 4976.884 us; speedup vs baseline: 1.9561x; 1.0620x over previous
//
#include <hip/hip_runtime.h>
#include <stdint.h>

#define B_ 32
#define T_ 256
#define DI_ 512
#define H_ 1024

// LDS row stride: MUST be a multiple of 8 shorts (16B) -- R8 bisection proved
// stride 1036 (8B-aligned odd rows) splits every ds_*_b128 into 2 ops: +57%.
#define LSTR 1032

using f32x4 = __attribute__((ext_vector_type(4))) float;
using s16x8 = __attribute__((ext_vector_type(8))) short;

__device__ inline unsigned short f2bf(float x) {
    unsigned u = __float_as_uint(x);
    u += 0x7FFFu + ((u >> 16) & 1u);
    return (unsigned short)(u >> 16);
}
__device__ inline float bf2f(unsigned short h) { return __uint_as_float(((unsigned)h) << 16); }
__device__ inline float sigf(float x) { return 1.f / (1.f + __expf(-x)); }
__device__ inline float tanhf_(float x) { return 1.f - 2.f / (__expf(2.f * x) + 1.f); }

__device__ inline unsigned ldA32(const unsigned* p) {
    return __hip_atomic_load(p, __ATOMIC_RELAXED, __HIP_MEMORY_SCOPE_AGENT);
}
__device__ inline void stA32(unsigned* p, unsigned v) {
    __hip_atomic_store(p, v, __ATOMIC_RELAXED, __HIP_MEMORY_SCOPE_AGENT);
}
__device__ inline unsigned long long ldA64(const unsigned long long* p) {
    return __hip_atomic_load(p, __ATOMIC_RELAXED, __HIP_MEMORY_SCOPE_AGENT);
}
__device__ inline void stA64(unsigned long long* p, unsigned long long v) {
    __hip_atomic_store(p, v, __ATOMIC_RELAXED, __HIP_MEMORY_SCOPE_AGENT);
}

// ---------------- conversion kernels ----------------

__global__ void conv_inputs_k(const float* __restrict__ in, unsigned short* __restrict__ out) {
    int idx = blockIdx.x * 256 + threadIdx.x;
    int d = (idx & 127) * 4;
    int row = idx >> 7;
    int t = row >> 5, b = row & 31;
    float4 v = *(const float4*)(in + ((size_t)b * T_ + t) * DI_ + d);
    unsigned long long p = (unsigned long long)f2bf(v.x)
        | ((unsigned long long)f2bf(v.y) << 16)
        | ((unsigned long long)f2bf(v.z) << 32)
        | ((unsigned long long)f2bf(v.w) << 48);
    *(unsigned long long*)(out + (size_t)row * DI_ + d) = p;
}

__global__ void conv_w_k(const float* __restrict__ src, unsigned short* __restrict__ dst,
                         int rowStride, int colOff, int K, int total4) {
    int idx = blockIdx.x * 256 + threadIdx.x;
    if (idx >= total4) return;
    int K4 = K >> 2;
    int r = idx / K4;
    int k = (idx - r * K4) << 2;
    float4 v = *(const float4*)(src + (size_t)r * rowStride + colOff + k);
    unsigned long long p = (unsigned long long)f2bf(v.x)
        | ((unsigned long long)f2bf(v.y) << 16)
        | ((unsigned long long)f2bf(v.z) << 32)
        | ((unsigned long long)f2bf(v.w) << 48);
    *(unsigned long long*)(dst + (size_t)r * K + k) = p;
}

__global__ void bias0_k(const float* __restrict__ a, const float* __restrict__ b, float* __restrict__ o) {
    int i = blockIdx.x * 256 + threadIdx.x;
    if (i < 4 * H_) o[i] = a[i] + b[i];
}

// ---------------- big parallel projection GEMM ----------------
__global__ __launch_bounds__(256) void proj_gemm_k(
    const unsigned short* __restrict__ A, const unsigned short* __restrict__ W,
    const float* __restrict__ bias, unsigned short* __restrict__ out, int K, int N) {
    __shared__ unsigned short Al[128 * 56];
    __shared__ unsigned short Bl[128 * 56];
    const int tid = threadIdx.x;
    const int lane = tid & 63, wave = tid >> 6;
    const int quad = lane >> 4, l16 = lane & 15;
    const int wm = (wave >> 1) * 64, wn = (wave & 1) * 64;
    const int bm = blockIdx.x, bn = blockIdx.y;
    const int srow = tid >> 1, shalf = tid & 1;
    const unsigned short* Ab = A + (size_t)(bm * 128 + srow) * K + shalf * 16;
    const unsigned short* Wb = W + (size_t)(bn * 128 + srow) * K + shalf * 16;

    f32x4 acc[4][4];
#pragma unroll
    for (int i = 0; i < 4; i++)
#pragma unroll
        for (int j = 0; j < 4; j++) acc[i][j] = (f32x4){0.f, 0.f, 0.f, 0.f};

    for (int kb = 0; kb < K; kb += 32) {
        s16x8 a0 = *(const s16x8*)(Ab + kb);
        s16x8 a1 = *(const s16x8*)(Ab + kb + 8);
        s16x8 b0 = *(const s16x8*)(Wb + kb);
        s16x8 b1 = *(const s16x8*)(Wb + kb + 8);
        __syncthreads();
        *(s16x8*)(&Al[srow * 56 + shalf * 16]) = a0;
        *(s16x8*)(&Al[srow * 56 + shalf * 16 + 8]) = a1;
        *(s16x8*)(&Bl[srow * 56 + shalf * 16]) = b0;
        *(s16x8*)(&Bl[srow * 56 + shalf * 16 + 8]) = b1;
        __syncthreads();
        s16x8 af[4], bf[4];
#pragma unroll
        for (int mt = 0; mt < 4; mt++) af[mt] = *(const s16x8*)(&Al[(wm + mt * 16 + l16) * 56 + quad * 8]);
#pragma unroll
        for (int nt = 0; nt < 4; nt++) bf[nt] = *(const s16x8*)(&Bl[(wn + nt * 16 + l16) * 56 + quad * 8]);
#pragma unroll
        for (int mt = 0; mt < 4; mt++)
#pragma unroll
            for (int nt = 0; nt < 4; nt++)
                acc[mt][nt] = __builtin_amdgcn_mfma_f32_16x16x32_bf16(af[mt], bf[nt], acc[mt][nt], 0, 0, 0);
    }
#pragma unroll
    for (int nt = 0; nt < 4; nt++) {
        int col = bn * 128 + wn + nt * 16 + l16;
        float bv = bias[col];
#pragma unroll
        for (int mt = 0; mt < 4; mt++) {
#pragma unroll
            for (int r = 0; r < 4; r++) {
                int rowg = bm * 128 + wm + mt * 16 + quad * 4 + r;
                out[(size_t)rowg * N + col] = f2bf(acc[mt][nt][r] + bv);
            }
        }
    }
}

// ---------------- paired persistent recurrence (layer-wavefront) ----------------
// R10 = R9 + COMPLETE register hoisting of time-invariant W fragments.
// R9 lesson: beat time tracks per-beat streamed-load work ~1:1 (removing
// 2x32 loads gave -2.3us/beat).  Remaining streamed W per beat:
//   A waves 0-1: secondary jobL = 32 global loads (latency-exposed, no TLP)
//   B waves 0-1: secondary jobP = 32 ds_read_b128
// Both have time-invariant rows (rr = 32+l16) -> hoist as wLs / wPs.
// A's NGA=5 secondary jobP keeps streaming LDS (cheap; saves registers).
template <int NGA, bool CAA, bool WRB>
__global__ __launch_bounds__(256, 1) void pairk(
    const float* __restrict__ WsrcA, int wStrideA, int wColOffA,
    const unsigned short* __restrict__ preA, int NA,
    const unsigned short* __restrict__ clowA,
    unsigned short* __restrict__ hbufA,
    const unsigned short* __restrict__ WstreamL,
    const float* __restrict__ biasL,
    unsigned short* __restrict__ ring,
    const float* __restrict__ WsrcB,
    unsigned short* __restrict__ hbufB,
    unsigned short* __restrict__ hrowB,
    unsigned short* __restrict__ cbufB,
    float* __restrict__ outh, float* __restrict__ outc,
    unsigned* __restrict__ flags) {

    __shared__ unsigned short wl[41 * LSTR];              // W_prev rows (+1 zero row)
    __shared__ unsigned short hl[32 * LSTR];              // staged h(t-1)
    __shared__ float gl[32 * 41];                         // own-matvec output
    __shared__ alignas(16) unsigned short gx[1536];       // A: pre(t-1) bf16 | B: staged block
    __shared__ alignas(16) unsigned short csh[2][256];    // A: c history (for emission)
    __shared__ alignas(16) unsigned short hsh[256];
    __shared__ float blds[40];                            // A: bias of layer l+1
    __shared__ unsigned epoch;

    const int tid = threadIdx.x;
    const int lane = tid & 63, wave = tid >> 6;
    const int quad = lane >> 4, l16 = lane & 15;
    const bool isA = (int)blockIdx.x < 128;
    const int wgl = (int)blockIdx.x & 127;
    unsigned* hflag = flags + (isA ? 0 : 128);
    unsigned* preflag = flags + 256;
    unsigned* bflag = flags + 384;
    const int u = tid & 7, b = tid >> 3;
    const int unit = wgl * 8 + u;
    const int mtile = wave & 1, ntile = wave >> 1;
    const s16x8 zv = {0, 0, 0, 0, 0, 0, 0, 0};

    if (tid == 0) epoch = 0;

    auto stageH = [&](const unsigned short* hb, int tsrc) {
        const int scol = wave * 256 + (lane & 31) * 8;
        const int r0 = lane >> 5;
        const unsigned short* hbase = hb + (size_t)tsrc * (B_ * H_) + scol;
        s16x8 hv[16];
#pragma unroll
        for (int i = 0; i < 16; i++) hv[i] = *(const s16x8*)(hbase + (size_t)(r0 + 2 * i) * H_);
#pragma unroll
        for (int i = 0; i < 16; i++) *(s16x8*)(&hl[(r0 + 2 * i) * LSTR + scol]) = hv[i];
    };

    if (isA) {
        // =================== ROLE A ===================
        constexpr int ROWS = NGA * 8;
        constexpr int NT = (ROWS + 15) / 16;
        for (int i = tid; i < ROWS * 1024; i += 256) {
            int r = i >> 10, k = i & 1023;
            wl[r * LSTR + k] =
                f2bf(WsrcA[(size_t)((r >> 3) * H_ + wgl * 8 + (r & 7)) * wStrideA + wColOffA + k]);
        }
        for (int k = tid; k < LSTR; k += 256) wl[ROWS * LSTR + k] = 0;
        for (int i = tid; i < 40; i += 256) blds[i] = biasL[(i >> 3) * H_ + wgl * 8 + (i & 7)];

        float cst = 0.f;
        unsigned short pg[NGA];
        unsigned short clw = 0;
#pragma unroll
        for (int g = 0; g < NGA; g++) pg[g] = preA[(size_t)b * NA + g * H_ + unit];
        if (CAA) clw = clowA[(size_t)b * H_ + unit];
        __syncthreads();  // wl ready

        // ---- hoist W fragments into registers (time-invariant) ----
        s16x8 wP[32], wL[32], wLs[32];
        {
            int br = ntile * 16 + l16;
            if (br >= ROWS) br = ROWS;
            const unsigned short* wr = &wl[br * LSTR + quad * 8];
#pragma unroll
            for (int c = 0; c < 8; c++)
#pragma unroll
                for (int j = 0; j < 4; j++)
                    wP[c * 4 + j] = *(const s16x8*)(wr + c * 128 + j * 32);
        }
        {
            int rr = ntile * 16 + l16;  // <= 31 < 40: always valid
            const unsigned short* sp =
                WstreamL + (size_t)((rr >> 3) * H_ + wgl * 8 + (rr & 7)) * H_ + quad * 8;
#pragma unroll
            for (int c = 0; c < 8; c++)
#pragma unroll
                for (int j = 0; j < 4; j++)
                    wL[c * 4 + j] = *(const s16x8*)(sp + c * 128 + j * 32);
        }
        {
            int rr = 32 + l16;  // secondary jobL rows; valid if < 40
            bool vLs = rr < 40;
            int g = vLs ? (rr >> 3) : 0;
            const unsigned short* sp =
                WstreamL + (size_t)(g * H_ + wgl * 8 + (rr & 7)) * H_ + quad * 8;
#pragma unroll
            for (int c = 0; c < 8; c++)
#pragma unroll
                for (int j = 0; j < 4; j++)
                    wLs[c * 4 + j] = vLs ? *(const s16x8*)(sp + c * 128 + j * 32) : zv;
        }

        auto pollA = [&](unsigned tgt, unsigned btgt, bool useB) {
            if (wave == 0) {
                for (;;) {
                    unsigned f0 = ldA32(hflag + lane);
                    unsigned f1 = ldA32(hflag + 64 + lane);
                    unsigned mn = f0 < f1 ? f0 : f1;
                    bool ok = mn >= tgt;
                    if (useB) ok = ok && (ldA32(bflag + wgl) >= btgt);
                    if (__all((int)ok)) break;
                    __builtin_amdgcn_s_sleep(2);
                }
                __hip_atomic_store(&epoch, tgt, __ATOMIC_RELAXED, __HIP_MEMORY_SCOPE_WORKGROUP);
            } else {
                while (__hip_atomic_load(&epoch, __ATOMIC_RELAXED, __HIP_MEMORY_SCOPE_WORKGROUP) < tgt)
                    __builtin_amdgcn_s_sleep(1);
            }
            asm volatile("" ::: "memory");
        };

        auto jobPreg = [&]() {
            const unsigned short* ar = &hl[(mtile * 16 + l16) * LSTR + quad * 8];
            f32x4 a0 = (f32x4){0.f, 0.f, 0.f, 0.f}, a1 = a0, a2 = a0, a3 = a0;
#pragma unroll
            for (int c = 0; c < 8; c++) {
                a0 = __builtin_amdgcn_mfma_f32_16x16x32_bf16(*(const s16x8*)(ar + c * 128), wP[c * 4 + 0], a0, 0, 0, 0);
                a1 = __builtin_amdgcn_mfma_f32_16x16x32_bf16(*(const s16x8*)(ar + c * 128 + 32), wP[c * 4 + 1], a1, 0, 0, 0);
                a2 = __builtin_amdgcn_mfma_f32_16x16x32_bf16(*(const s16x8*)(ar + c * 128 + 64), wP[c * 4 + 2], a2, 0, 0, 0);
                a3 = __builtin_amdgcn_mfma_f32_16x16x32_bf16(*(const s16x8*)(ar + c * 128 + 96), wP[c * 4 + 3], a3, 0, 0, 0);
            }
            f32x4 a = (a0 + a1) + (a2 + a3);
            int n = ntile * 16 + l16;
            if (n < ROWS) {
#pragma unroll
                for (int r = 0; r < 4; r++) gl[(mtile * 16 + quad * 4 + r) * 41 + n] = a[r];
            }
        };

        auto jobP = [&](int m, int nt) {  // secondary: streams wl from LDS (cheap)
            const unsigned short* ar = &hl[(m * 16 + l16) * LSTR + quad * 8];
            int br = nt * 16 + l16;
            if (br >= ROWS) br = ROWS;
            const unsigned short* wr = &wl[br * LSTR + quad * 8];
            f32x4 a0 = (f32x4){0.f, 0.f, 0.f, 0.f}, a1 = a0, a2 = a0, a3 = a0;
#pragma unroll
            for (int kb = 0; kb < 1024; kb += 128) {
                a0 = __builtin_amdgcn_mfma_f32_16x16x32_bf16(*(const s16x8*)(ar + kb), *(const s16x8*)(wr + kb), a0, 0, 0, 0);
                a1 = __builtin_amdgcn_mfma_f32_16x16x32_bf16(*(const s16x8*)(ar + kb + 32), *(const s16x8*)(wr + kb + 32), a1, 0, 0, 0);
                a2 = __builtin_amdgcn_mfma_f32_16x16x32_bf16(*(const s16x8*)(ar + kb + 64), *(const s16x8*)(wr + kb + 64), a2, 0, 0, 0);
                a3 = __builtin_amdgcn_mfma_f32_16x16x32_bf16(*(const s16x8*)(ar + kb + 96), *(const s16x8*)(wr + kb + 96), a3, 0, 0, 0);
            }
            f32x4 a = (a0 + a1) + (a2 + a3);
            int n = nt * 16 + l16;
            if (n < ROWS) {
#pragma unroll
                for (int r = 0; r < 4; r++) gl[(m * 16 + quad * 4 + r) * 41 + n] = a[r];
            }
        };

        auto jobLreg = [&]() {
            const unsigned short* ar = &hl[(mtile * 16 + l16) * LSTR + quad * 8];
            int rr = ntile * 16 + l16;
            f32x4 a0 = (f32x4){0.f, 0.f, 0.f, 0.f}, a1 = a0, a2 = a0, a3 = a0;
#pragma unroll
            for (int c = 0; c < 8; c++) {
                a0 = __builtin_amdgcn_mfma_f32_16x16x32_bf16(*(const s16x8*)(ar + c * 128), wL[c * 4 + 0], a0, 0, 0, 0);
                a1 = __builtin_amdgcn_mfma_f32_16x16x32_bf16(*(const s16x8*)(ar + c * 128 + 32), wL[c * 4 + 1], a1, 0, 0, 0);
                a2 = __builtin_amdgcn_mfma_f32_16x16x32_bf16(*(const s16x8*)(ar + c * 128 + 64), wL[c * 4 + 2], a2, 0, 0, 0);
                a3 = __builtin_amdgcn_mfma_f32_16x16x32_bf16(*(const s16x8*)(ar + c * 128 + 96), wL[c * 4 + 3], a3, 0, 0, 0);
            }
            f32x4 a = (a0 + a1) + (a2 + a3);
            if (rr < 40) {
#pragma unroll
                for (int r = 0; r < 4; r++)
                    gx[(mtile * 16 + quad * 4 + r) * 40 + rr] = f2bf(a[r] + blds[rr]);
            }
        };

        auto jobLsecReg = [&](int m) {  // secondary jobL, register W
            const unsigned short* ar = &hl[(m * 16 + l16) * LSTR + quad * 8];
            int rr = 32 + l16;
            f32x4 a0 = (f32x4){0.f, 0.f, 0.f, 0.f}, a1 = a0, a2 = a0, a3 = a0;
#pragma unroll
            for (int c = 0; c < 8; c++) {
                a0 = __builtin_amdgcn_mfma_f32_16x16x32_bf16(*(const s16x8*)(ar + c * 128), wLs[c * 4 + 0], a0, 0, 0, 0);
                a1 = __builtin_amdgcn_mfma_f32_16x16x32_bf16(*(const s16x8*)(ar + c * 128 + 32), wLs[c * 4 + 1], a1, 0, 0, 0);
                a2 = __builtin_amdgcn_mfma_f32_16x16x32_bf16(*(const s16x8*)(ar + c * 128 + 64), wLs[c * 4 + 2], a2, 0, 0, 0);
                a3 = __builtin_amdgcn_mfma_f32_16x16x32_bf16(*(const s16x8*)(ar + c * 128 + 96), wLs[c * 4 + 3], a3, 0, 0, 0);
            }
            f32x4 a = (a0 + a1) + (a2 + a3);
            if (rr < 40) {
#pragma unroll
                for (int r = 0; r < 4; r++)
                    gx[(m * 16 + quad * 4 + r) * 40 + rr] = f2bf(a[r] + blds[rr]);
            }
        };

        auto packIssue = [&](int tsrc) {  // wave1: gx(pre(tsrc)) + csh -> ring slot
            unsigned short* base = ring + ((size_t)(tsrc & 7) * 128 + wgl) * 1536;
#pragma unroll
            for (int k = 0; k < 3; k++) {
                int off = (k * 64 + lane) * 8;
                const unsigned long long* src = (off < 1280)
                    ? (const unsigned long long*)&gx[off]
                    : (const unsigned long long*)&csh[tsrc & 1][off - 1280];
                unsigned long long* dst = (unsigned long long*)(base + off);
                stA64(dst, src[0]);
                stA64(dst + 1, src[1]);
            }
        };

        for (int t = 0; t < T_; ++t) {
            if (t > 0) {
                pollA((unsigned)t, (unsigned)(t - 6), t > 6);
                __syncthreads();  // all slack jobL done before hl overwrite
                stageH(hbufA, t - 1);
            }
            __syncthreads();  // hl ready
            if (t > 1 && wave == 1) packIssue(t - 2);
            if (t > 0) {
                jobPreg();
                if (NT == 3 && wave < 2) jobP(wave, 2);
            }
            __syncthreads();  // gl ready (and pack reads done)
            {
                float gate[NGA];
#pragma unroll
                for (int g = 0; g < NGA; g++)
                    gate[g] = bf2f(pg[g]) + ((t > 0) ? gl[b * 41 + g * 8 + u] : 0.f);
                float clv = CAA ? bf2f(clw) : 0.f;
                if (t + 1 < T_) {
#pragma unroll
                    for (int g = 0; g < NGA; g++)
                        pg[g] = preA[(size_t)((t + 1) * B_ + b) * NA + g * H_ + unit];
                    if (CAA) clw = clowA[(size_t)((t + 1) * B_ + b) * H_ + unit];
                }
                float cnew, hval;
                if (CAA) {
                    float iv = sigf(gate[0]);
                    float fp = sigf(gate[1] + 1.f);
                    float fl = sigf(gate[2] + 1.f);
                    float uu = tanhf_(gate[3]);
                    float ov = sigf(gate[4]);
                    cnew = cst * fp + clv * fl + uu * iv;
                    hval = ov * tanhf_(cnew);
                } else {
                    float iv = sigf(gate[0]);
                    float fv = sigf(gate[1]);
                    float gv = tanhf_(gate[2]);
                    float ov = sigf(gate[3]);
                    cnew = fv * cst + iv * gv;
                    hval = ov * tanhf_(cnew);
                }
                cst = cnew;
                csh[t & 1][tid] = f2bf(cnew);
                hsh[tid] = f2bf(hval);
            }
            __syncthreads();  // hsh/csh ready
            if (wave == 3) {
                if (lane < 32) {
                    const unsigned long long* s = (const unsigned long long*)&hsh[lane * 8];
                    unsigned long long* d =
                        (unsigned long long*)(hbufA + ((size_t)t * B_ + lane) * H_ + wgl * 8);
                    stA64(d, s[0]);
                    stA64(d + 1, s[1]);
                }
                asm volatile("s_waitcnt vmcnt(0)" ::: "memory");
                if (lane == 0) stA32(hflag + wgl, (unsigned)(t + 1));
            }
            if (t > 1 && wave == 1) {
                asm volatile("s_waitcnt vmcnt(0)" ::: "memory");
                if (lane == 0) stA32(preflag + wgl, (unsigned)(t - 1));
            }
            // slack: emission matvec pre(t-1) from hl = h(t-1)
            if (t > 0) {
                jobLreg();
                if (wave < 2) jobLsecReg(wave);
            }
        }
        // epilogue: publish pre(254) (in gx) then compute+publish pre(255)
        pollA(256u, 250u, true);
        __syncthreads();
        stageH(hbufA, T_ - 1);
        __syncthreads();
        if (wave == 1) packIssue(T_ - 2);
        __syncthreads();  // pack reads of gx done before overwrite
        jobLreg();
        if (wave < 2) jobLsecReg(wave);
        __syncthreads();  // gx = pre(255) ready
        if (wave == 1) {
            packIssue(T_ - 1);
            asm volatile("s_waitcnt vmcnt(0)" ::: "memory");
            if (lane == 0) stA32(preflag + wgl, 256u);
        }
    } else {
        // =================== ROLE B ===================
        constexpr int ROWS = 40;
        for (int i = tid; i < ROWS * 1024; i += 256) {
            int r = i >> 10, k = i & 1023;
            wl[r * LSTR + k] =
                f2bf(WsrcB[(size_t)((r >> 3) * H_ + wgl * 8 + (r & 7)) * 2048 + 1024 + k]);
        }
        for (int k = tid; k < LSTR; k += 256) wl[ROWS * LSTR + k] = 0;
        float cst = 0.f;
        __syncthreads();

        // hoist primary + secondary jobP W fragments
        s16x8 wP[32], wPs[32];
        {
            int br = ntile * 16 + l16;
            if (br >= ROWS) br = ROWS;
            const unsigned short* wr = &wl[br * LSTR + quad * 8];
#pragma unroll
            for (int c = 0; c < 8; c++)
#pragma unroll
                for (int j = 0; j < 4; j++)
                    wP[c * 4 + j] = *(const s16x8*)(wr + c * 128 + j * 32);
        }
        {
            int br = 32 + l16;
            if (br >= ROWS) br = ROWS;  // zero row for l16 >= 8
            const unsigned short* wr = &wl[br * LSTR + quad * 8];
#pragma unroll
            for (int c = 0; c < 8; c++)
#pragma unroll
                for (int j = 0; j < 4; j++)
                    wPs[c * 4 + j] = *(const s16x8*)(wr + c * 128 + j * 32);
        }

        auto jobPreg = [&]() {
            const unsigned short* ar = &hl[(mtile * 16 + l16) * LSTR + quad * 8];
            f32x4 a0 = (f32x4){0.f, 0.f, 0.f, 0.f}, a1 = a0, a2 = a0, a3 = a0;
#pragma unroll
            for (int c = 0; c < 8; c++) {
                a0 = __builtin_amdgcn_mfma_f32_16x16x32_bf16(*(const s16x8*)(ar + c * 128), wP[c * 4 + 0], a0, 0, 0, 0);
                a1 = __builtin_amdgcn_mfma_f32_16x16x32_bf16(*(const s16x8*)(ar + c * 128 + 32), wP[c * 4 + 1], a1, 0, 0, 0);
                a2 = __builtin_amdgcn_mfma_f32_16x16x32_bf16(*(const s16x8*)(ar + c * 128 + 64), wP[c * 4 + 2], a2, 0, 0, 0);
                a3 = __builtin_amdgcn_mfma_f32_16x16x32_bf16(*(const s16x8*)(ar + c * 128 + 96), wP[c * 4 + 3], a3, 0, 0, 0);
            }
            f32x4 a = (a0 + a1) + (a2 + a3);
            int n = ntile * 16 + l16;
            if (n < ROWS) {
#pragma unroll
                for (int r = 0; r < 4; r++) gl[(mtile * 16 + quad * 4 + r) * 41 + n] = a[r];
            }
        };

        auto jobPsecReg = [&](int m) {
            const unsigned short* ar = &hl[(m * 16 + l16) * LSTR + quad * 8];
            f32x4 a0 = (f32x4){0.f, 0.f, 0.f, 0.f}, a1 = a0, a2 = a0, a3 = a0;
#pragma unroll
            for (int c = 0; c < 8; c++) {
                a0 = __builtin_amdgcn_mfma_f32_16x16x32_bf16(*(const s16x8*)(ar + c * 128), wPs[c * 4 + 0], a0, 0, 0, 0);
                a1 = __builtin_amdgcn_mfma_f32_16x16x32_bf16(*(const s16x8*)(ar + c * 128 + 32), wPs[c * 4 + 1], a1, 0, 0, 0);
                a2 = __builtin_amdgcn_mfma_f32_16x16x32_bf16(*(const s16x8*)(ar + c * 128 + 64), wPs[c * 4 + 2], a2, 0, 0, 0);
                a3 = __builtin_amdgcn_mfma_f32_16x16x32_bf16(*(const s16x8*)(ar + c * 128 + 96), wPs[c * 4 + 3], a3, 0, 0, 0);
            }
            f32x4 a = (a0 + a1) + (a2 + a3);
            int n = 32 + l16;
            if (n < ROWS) {
#pragma unroll
                for (int r = 0; r < 4; r++) gl[(m * 16 + quad * 4 + r) * 41 + n] = a[r];
            }
        };

        for (int t = 0; t < T_; ++t) {
            if (wave == 0) {
                for (;;) {
                    bool ok = ldA32(preflag + wgl) >= (unsigned)(t + 1);
                    if (t > 0) {
                        unsigned f0 = ldA32(hflag + lane);
                        unsigned f1 = ldA32(hflag + 64 + lane);
                        unsigned mn = f0 < f1 ? f0 : f1;
                        ok = ok && (mn >= (unsigned)t);
                    }
                    if (__all((int)ok)) break;
                    __builtin_amdgcn_s_sleep(2);
                }
                __hip_atomic_store(&epoch, (unsigned)(t + 1), __ATOMIC_RELAXED, __HIP_MEMORY_SCOPE_WORKGROUP);
            } else {
                while (__hip_atomic_load(&epoch, __ATOMIC_RELAXED, __HIP_MEMORY_SCOPE_WORKGROUP) < (unsigned)(t + 1))
                    __builtin_amdgcn_s_sleep(1);
            }
            asm volatile("" ::: "memory");
            if (t > 0) stageH(hbufB, t - 1);
            if (wave == 0) {
                // consume block (sc1: ring slots are reused)
                const unsigned short* base = ring + ((size_t)(t & 7) * 128 + wgl) * 1536;
#pragma unroll
                for (int k = 0; k < 3; k++) {
                    int off = (k * 64 + lane) * 8;
                    const unsigned long long* sp = (const unsigned long long*)(base + off);
                    unsigned long long v0 = ldA64(sp);
                    unsigned long long v1 = ldA64(sp + 1);
                    *(unsigned long long*)(&gx[off]) = v0;
                    *(unsigned long long*)(&gx[off + 4]) = v1;
                }
                asm volatile("s_waitcnt vmcnt(0)" ::: "memory");
                if (lane == 0) stA32(bflag + wgl, (unsigned)(t + 1));
            }
            __syncthreads();  // hl + gx ready
            if (t > 0) {
                jobPreg();
                if (wave < 2) jobPsecReg(wave);
            }
            __syncthreads();  // gl ready
            {
                float gate[5];
#pragma unroll
                for (int g = 0; g < 5; g++)
                    gate[g] = bf2f(gx[b * 40 + g * 8 + u]) + ((t > 0) ? gl[b * 41 + g * 8 + u] : 0.f);
                float clv = bf2f(gx[1280 + b * 8 + u]);
                float iv = sigf(gate[0]);
                float fp = sigf(gate[1] + 1.f);
                float fl = sigf(gate[2] + 1.f);
                float uu = tanhf_(gate[3]);
                float ov = sigf(gate[4]);
                float cnew = cst * fp + clv * fl + uu * iv;
                float hval = ov * tanhf_(cnew);
                cst = cnew;
                hsh[tid] = f2bf(hval);
                if (WRB) {
                    outh[((size_t)b * T_ + t) * H_ + unit] = hval;
                    outc[((size_t)b * T_ + t) * H_ + unit] = cnew;
                } else {
                    cbufB[((size_t)t * B_ + b) * H_ + unit] = f2bf(cnew);
                }
            }
            __syncthreads();  // hsh ready
            if (!WRB && tid < 32)
                *(s16x8*)(hrowB + ((size_t)t * B_ + tid) * H_ + wgl * 8) = *(const s16x8*)&hsh[tid * 8];
            if (wave == 3) {
                if (lane < 32) {
                    const unsigned long long* s = (const unsigned long long*)&hsh[lane * 8];
                    unsigned long long* d =
                        (unsigned long long*)(hbufB + ((size_t)t * B_ + lane) * H_ + wgl * 8);
                    stA64(d, s[0]);
                    stA64(d + 1, s[1]);
                }
                asm volatile("s_waitcnt vmcnt(0)" ::: "memory");
                if (lane == 0) stA32(hflag + wgl, (unsigned)(t + 1));
            }
        }
    }
}

// ---------------- launcher ----------------

extern "C" void kernel_launch(void* const* d_in, const int* in_sizes, int n_in,
                              void* d_out, int out_size, void* d_ws, size_t ws_size,
                              hipStream_t stream) {
    const float* inputs = (const float*)d_in[0];
    const float* W_ih0 = (const float*)d_in[1];
    const float* W_hh0 = (const float*)d_in[2];
    const float* b_ih0 = (const float*)d_in[3];
    const float* b_hh0 = (const float*)d_in[4];
    const float* W_ca = (const float*)d_in[5];
    const float* b_ca = (const float*)d_in[6];
    float* out = (float*)d_out;

    char* ws = (char*)d_ws;
    unsigned* flags = (unsigned*)ws;                                   // 4 KB (2 pair zones)
    unsigned short* A0 = (unsigned short*)(ws + 4096);                 // 8 MB
    unsigned short* R1 = A0 + (size_t)8192 * 512;                      // 10.5 MB bf16 weight staging
    float* bc0 = (float*)((char*)R1 + 10485760);                       // 16 KB
    unsigned short* pre = (unsigned short*)((char*)bc0 + 16384);       // 84 MB
    unsigned short* hA = pre + (size_t)8192 * 5120;                    // 16 MB
    unsigned short* hB = hA + (size_t)8192 * 1024;                     // 16 MB
    unsigned short* hrow1 = hB + (size_t)8192 * 1024;                  // 16 MB
    unsigned short* c1 = hrow1 + (size_t)8192 * 1024;                  // 16 MB
    unsigned short* ring = c1 + (size_t)8192 * 1024;                   // 3 MB

    hipMemsetAsync(flags, 0, 4096, stream);

    // layer-0 input projection
    conv_inputs_k<<<4096, 256, 0, stream>>>(inputs, A0);
    conv_w_k<<<2048, 256, 0, stream>>>(W_ih0, R1, 512, 0, 512, 4096 * 128);
    bias0_k<<<16, 256, 0, stream>>>(b_ih0, b_hh0, bc0);
    proj_gemm_k<<<dim3(64, 32), 256, 0, stream>>>(A0, R1, bc0, pre, 512, 4096);

    // pair 1: A = layer0 (emits pre_1,c_0), B = layer1 (writes hrow1, c1)
    conv_w_k<<<5120, 256, 0, stream>>>(W_ca + (size_t)0 * 5120 * 2048, R1, 2048, 0, 1024, 5120 * 256);
    pairk<4, false, false><<<256, 256, 0, stream>>>(
        W_hh0, 1024, 0, pre, 4096, nullptr, hA,
        R1, b_ca + 0 * 5120, ring,
        W_ca + (size_t)0 * 5120 * 2048, hB, hrow1, c1, nullptr, nullptr, flags);

    // layer-2 input projection over full h_1
    conv_w_k<<<5120, 256, 0, stream>>>(W_ca + (size_t)1 * 5120 * 2048, R1, 2048, 0, 1024, 5120 * 256);
    proj_gemm_k<<<dim3(64, 40), 256, 0, stream>>>(hrow1, R1, b_ca + 1 * 5120, pre, 1024, 5120);

    // pair 2: A = layer2 (consumes pre_2 + c1, emits pre_3,c_2), B = layer3 (writes out)
    conv_w_k<<<5120, 256, 0, stream>>>(W_ca + (size_t)2 * 5120 * 2048, R1, 2048, 0, 1024, 5120 * 256);
    pairk<5, true, true><<<256, 256, 0, stream>>>(
        W_ca + (size_t)1 * 5120 * 2048, 2048, 1024, pre, 5120, c1, hA,
        R1, b_ca + 2 * 5120, ring,
        W_ca + (size_t)2 * 5120 * 2048, hB, nullptr, nullptr,
        out, out + (size_t)8192 * 1024, flags + 512);
}